// Round 6
// baseline (243.434 us; speedup 1.0000x reference)
//
#include <hip/hip_runtime.h>

// Leaky LIF SNN forward, x/spk: [T=128, B*N=262144] fp32.
//   reset_t = H(mem_{t-1} - 1); mem_t = 0.5*mem_{t-1} + x_t - reset_t; spk_t = H(mem_t - 1)
//
// R1-R3: 2.45 TB/s invariant across occupancy/pipeline shape -> DRAM-locality
// bound (1 MB row stride, small drifting per-block visits). R4 (2 phases,
// 1 KB visits, 8 waves/CU): small gain (~72 us). R5 scales the granule axis:
// 1024-thread blocks -> 4 KB contiguous visit per block per row; 4 T-phases
// with exact warmup recompute -> 256 blocks = 1/CU, 16 waves/CU. Phase bits
// high so all phases of a chunk share an XCD/L2 (warmup re-reads cache-hit).
// Ring is unroll-by-D so all buf indices are static (no scratch).
// (R5 bench attempt hit GPUAcquisitionTimeout — identical kernel resubmitted.)

#define T_STEPS 128
#define PHASES 4
#define ACTIVE (T_STEPS / PHASES)   // 32 rows stored per phase
#define D 8                         // rolling prefetch depth (rows in flight)

__device__ __forceinline__ float4 lif_step(float4& mem, const float4 v) {
    mem.x = 0.5f * mem.x + v.x - (mem.x > 1.0f ? 1.0f : 0.0f);
    mem.y = 0.5f * mem.y + v.y - (mem.y > 1.0f ? 1.0f : 0.0f);
    mem.z = 0.5f * mem.z + v.z - (mem.z > 1.0f ? 1.0f : 0.0f);
    mem.w = 0.5f * mem.w + v.w - (mem.w > 1.0f ? 1.0f : 0.0f);
    float4 s;
    s.x = mem.x > 1.0f ? 1.0f : 0.0f;
    s.y = mem.y > 1.0f ? 1.0f : 0.0f;
    s.z = mem.z > 1.0f ? 1.0f : 0.0f;
    s.w = mem.w > 1.0f ? 1.0f : 0.0f;
    return s;
}

__global__ __launch_bounds__(1024) void snn_leaky_fwd(const float4* __restrict__ x,
                                                      float4* __restrict__ out,
                                                      int n4) {
    // phase in HIGH bits: blocks {c, c+64, c+128, c+192} are all == c (mod 8)
    // -> same XCD under round-robin; warmup re-reads hit the shared L2.
    const int chunk = blockIdx.x & 63;          // 64 column chunks
    const int phase = blockIdx.x >> 6;          // 4 time phases
    const int col = chunk * 1024 + threadIdx.x; // float4 column index

    const float4* xp = x + col;
    float4* op = out + col;

    const int s = phase * ACTIVE;               // first stored row
    const int tEnd = s + ACTIVE;                // one past last stored row

    float4 buf[D];
    float4 mem = make_float4(0.f, 0.f, 0.f, 0.f);

    // prologue: fill the ring (tEnd >= 32 > D always)
#pragma unroll
    for (int u = 0; u < D; ++u) buf[u] = xp[(size_t)u * n4];

    // rolled outer loop over D-row batches, fully unrolled inner -> static
    // ring indices (registers, no scratch) and fine-grained per-slot vmcnt.
    for (int tb = 0; tb < tEnd; tb += D) {
        const bool active = (tb >= s);          // block-uniform branch
#pragma unroll
        for (int u = 0; u < D; ++u) {
            const int t = tb + u;
            const float4 v = buf[u];
            if (t + D < tEnd) buf[u] = xp[(size_t)(t + D) * n4];
            const float4 spk = lif_step(mem, v);
            if (active) op[(size_t)t * n4] = spk;
        }
    }
}

extern "C" void kernel_launch(void* const* d_in, const int* in_sizes, int n_in,
                              void* d_out, int out_size, void* d_ws, size_t ws_size,
                              hipStream_t stream) {
    const float4* x = (const float4*)d_in[0];
    float4* out = (float4*)d_out;

    const int total = in_sizes[0];            // T*B*N = 128*64*4096
    const int n4 = total / T_STEPS / 4;       // 65536 float4 columns

    // 64 chunks x 4 phases = 256 blocks x 1024 thr -> 1 block/CU, 16 waves/CU,
    // 4 KB contiguous per block per row visit.
    snn_leaky_fwd<<<PHASES * 64, 1024, 0, stream>>>(x, out, n4);
}

// Round 7
// 235.260 us; speedup vs baseline: 1.0347x; 1.0347x over previous
//
#include <hip/hip_runtime.h>
#include <stdint.h>

// Leaky LIF SNN forward, x/spk: [T=128, B*N=262144] fp32.
//   reset_t = H(mem_{t-1} - 1); mem_t = 0.5*mem_{t-1} + x_t - reset_t; spk_t = H(mem_t - 1)
//
// R1-R6: 2.2-2.5 TB/s invariant across occupancy/visit-size/pipeline shape.
// Last untested axis: the fine-grained MIX of strided reads + strided writes.
// R7: spikes are {0,1} -> pack 128 spikes/neuron into 4 uint32 bit-planes
// (4 MB workspace). K1 = pure strided-read recurrence + tiny packed writes.
// K2 = per-block contiguous 256 KB output spans: cache-hot plane reads ->
// perfectly sequential fp32 writes at fill rate.

#define T_STEPS 128
#define NWORDS 4          // 128 bits per neuron
#define D 24              // K1 rolling prefetch depth

__global__ __launch_bounds__(256) void snn_pack(const float* __restrict__ x,
                                                uint32_t* __restrict__ ws,  // [NWORDS][n] planes
                                                int n) {
    const int idx = blockIdx.x * blockDim.x + threadIdx.x;
    if (idx >= n) return;
    const float* xp = x + idx;

    float buf[D];
    float mem = 0.0f;
    uint32_t w0 = 0, w1 = 0, w2 = 0, w3 = 0;

#pragma unroll
    for (int u = 0; u < D; ++u) buf[u] = xp[(size_t)u * n];

#pragma unroll
    for (int t = 0; t < T_STEPS; ++t) {
        const float v = buf[t % D];                 // static index after unroll
        if (t + D < T_STEPS) buf[t % D] = xp[(size_t)(t + D) * n];
        mem = 0.5f * mem + v - (mem > 1.0f ? 1.0f : 0.0f);
        const uint32_t bit = (mem > 1.0f) ? 1u : 0u;
        if (t < 32)       w0 |= bit << (t & 31);
        else if (t < 64)  w1 |= bit << (t & 31);
        else if (t < 96)  w2 |= bit << (t & 31);
        else              w3 |= bit << (t & 31);
    }
    ws[(size_t)0 * n + idx] = w0;
    ws[(size_t)1 * n + idx] = w1;
    ws[(size_t)2 * n + idx] = w2;
    ws[(size_t)3 * n + idx] = w3;
}

__global__ __launch_bounds__(256) void snn_expand(const uint32_t* __restrict__ ws,
                                                  float4* __restrict__ out,
                                                  int n) {
    // block = (row t, quarter q): writes a contiguous 256 KB span of out row t.
    const int t = blockIdx.x >> 2;
    const int q = blockIdx.x & 3;
    const int n4 = n >> 2;              // float4s per row (65536)
    const int span4 = n4 >> 2;          // float4s per quarter (16384)
    const int sh = t & 31;

    const uint32_t* plane = ws + (size_t)(t >> 5) * n;
    // out float4 i covers neurons 4i..4i+3 -> plane words [4i..4i+3] = uint4 #i
    const uint4* wp4 = (const uint4*)plane + (size_t)q * span4;
    float4* op = out + (size_t)t * n4 + (size_t)q * span4;

    for (int i = threadIdx.x; i < span4; i += 256) {
        const uint4 w = wp4[i];
        float4 o;
        o.x = (float)((w.x >> sh) & 1u);
        o.y = (float)((w.y >> sh) & 1u);
        o.z = (float)((w.z >> sh) & 1u);
        o.w = (float)((w.w >> sh) & 1u);
        op[i] = o;
    }
}

// Fallback (ws too small): R3-style fused kernel, known-good at ~81 us.
__global__ __launch_bounds__(256) void snn_fused(const float* __restrict__ x,
                                                 float* __restrict__ out,
                                                 int n) {
    const int idx = blockIdx.x * blockDim.x + threadIdx.x;
    if (idx >= n) return;
    const float* xp = x + idx;
    float* op = out + idx;

    float buf[D];
    float mem = 0.0f;
#pragma unroll
    for (int u = 0; u < D; ++u) buf[u] = xp[(size_t)u * n];
#pragma unroll
    for (int t = 0; t < T_STEPS; ++t) {
        const float v = buf[t % D];
        if (t + D < T_STEPS) buf[t % D] = xp[(size_t)(t + D) * n];
        mem = 0.5f * mem + v - (mem > 1.0f ? 1.0f : 0.0f);
        const float spk = (mem > 1.0f) ? 1.0f : 0.0f;
        __builtin_nontemporal_store(spk, op + (size_t)t * n);
    }
}

extern "C" void kernel_launch(void* const* d_in, const int* in_sizes, int n_in,
                              void* d_out, int out_size, void* d_ws, size_t ws_size,
                              hipStream_t stream) {
    const float* x = (const float*)d_in[0];
    const int total = in_sizes[0];          // T*B*N = 128*64*4096
    const int n = total / T_STEPS;          // 262144 neurons

    const size_t ws_needed = (size_t)NWORDS * (size_t)n * sizeof(uint32_t); // 4 MB

    if (ws_size >= ws_needed) {
        uint32_t* ws = (uint32_t*)d_ws;
        snn_pack<<<(n + 255) / 256, 256, 0, stream>>>(x, ws, n);
        snn_expand<<<T_STEPS * 4, 256, 0, stream>>>(ws, (float4*)d_out, n);
    } else {
        snn_fused<<<(n + 255) / 256, 256, 0, stream>>>(x, (float*)d_out, n);
    }
}